// Round 1
// baseline (90.444 us; speedup 1.0000x reference)
//
#include <hip/hip_runtime.h>
#include <math.h>

// Problem shape (fixed by the reference): B=2048, D=1024, features = [2B, D].
constexpr int B = 2048;
constexpr int D = 1024;
constexpr int N2 = 2 * B;   // 4096 rows total

// ws float layout:
//   [0,   B)   dot_ss[i] = s_i · s_j          (j = (i+1)%B)
//   [B,  2B)   dot_tt[i] = t_i · t_j
//   [2B, 3B)   dot_st[i] = s_i · t_j
//   [3B, 4B)   dot_ts[i] = s_j · t_i
//   [4B, 5B)   sq_s[i]   = ||s_i||^2
//   [5B, 6B)   sq_t[i]   = ||t_i||^2
//   [6B, 6B+D) colsum[d] = sum_i f[i][d]
// total = 6*2048 + 1024 = 13312 floats = 53 KB

__global__ void mmd_init_colsum(float* colsum) {
    colsum[threadIdx.x] = 0.0f;   // 1024 threads, D=1024
}

// Column sums of the concatenated [4096, 1024] feature matrix.
// 256 blocks x 1024 threads; block b sums 16 rows; one float atomic per thread.
__global__ void mmd_colsum(const float* __restrict__ zs,
                           const float* __restrict__ zt,
                           float* __restrict__ colsum) {
    const int col = threadIdx.x;
    const int r0  = blockIdx.x * 16;
    float acc = 0.0f;
#pragma unroll
    for (int k = 0; k < 16; ++k) {
        const int r = r0 + k;
        const float* f = (r < B) ? (zs + (size_t)r * D) : (zt + (size_t)(r - B) * D);
        acc += f[col];
    }
    atomicAdd(&colsum[col], acc);
}

__device__ inline float wave_reduce_f(float v) {
#pragma unroll
    for (int off = 32; off > 0; off >>= 1) v += __shfl_down(v, off, 64);
    return v;
}

// One block per i: the 4 neighbor dot products + 2 row square-norms.
// 256 threads, one float4 per thread per row (D/4 = 256).
__global__ void mmd_dots(const float* __restrict__ zs,
                         const float* __restrict__ zt,
                         float* __restrict__ ws) {
    const int i   = blockIdx.x;
    const int j   = (i + 1) & (B - 1);     // B is a power of two
    const int tid = threadIdx.x;

    const float4* si = (const float4*)(zs + (size_t)i * D);
    const float4* sj = (const float4*)(zs + (size_t)j * D);
    const float4* ti = (const float4*)(zt + (size_t)i * D);
    const float4* tj = (const float4*)(zt + (size_t)j * D);

    const float4 a = si[tid];
    const float4 b = sj[tid];
    const float4 c = ti[tid];
    const float4 d = tj[tid];

    float vals[6];
    vals[0] = a.x*b.x + a.y*b.y + a.z*b.z + a.w*b.w;   // s_i . s_j
    vals[1] = c.x*d.x + c.y*d.y + c.z*d.z + c.w*d.w;   // t_i . t_j
    vals[2] = a.x*d.x + a.y*d.y + a.z*d.z + a.w*d.w;   // s_i . t_j
    vals[3] = b.x*c.x + b.y*c.y + b.z*c.z + b.w*c.w;   // s_j . t_i
    vals[4] = a.x*a.x + a.y*a.y + a.z*a.z + a.w*a.w;   // ||s_i||^2
    vals[5] = c.x*c.x + c.y*c.y + c.z*c.z + c.w*c.w;   // ||t_i||^2

    __shared__ float sred[6][4];
    const int lane = tid & 63;
    const int wav  = tid >> 6;
#pragma unroll
    for (int k = 0; k < 6; ++k) {
        float v = wave_reduce_f(vals[k]);
        if (lane == 0) sred[k][wav] = v;
    }
    __syncthreads();
    if (tid < 6) {
        float t = sred[tid][0] + sred[tid][1] + sred[tid][2] + sred[tid][3];
        ws[tid * B + i] = t;
    }
}

// Single block, 1024 threads: mean_d2 analytically, then the 8192 kernel
// evaluations and final double-precision reduction.
__global__ void mmd_finalize(const float* __restrict__ ws, float* __restrict__ out) {
    const float* dss    = ws;
    const float* dtt    = ws + B;
    const float* dst    = ws + 2 * B;
    const float* dts    = ws + 3 * B;
    const float* sqs    = ws + 4 * B;
    const float* sqt    = ws + 5 * B;
    const float* colsum = ws + 6 * B;

    __shared__ double red[1024];
    __shared__ double red2[1024];
    __shared__ double sh_mean;
    const int tid = threadIdx.x;

    // S = sum ||f_i||^2 ; V2 = ||colsum||^2
    double s = 0.0;
    for (int i = tid; i < B; i += 1024)
        s += (double)sqs[i] + (double)sqt[i];
    double cv = (double)colsum[tid];    // exactly 1024 threads / columns
    red[tid]  = s;
    red2[tid] = cv * cv;
    __syncthreads();
    for (int off = 512; off > 0; off >>= 1) {
        if (tid < off) { red[tid] += red[tid + off]; red2[tid] += red2[tid + off]; }
        __syncthreads();
    }
    if (tid == 0) {
        const double S  = red[0];
        const double V2 = red2[0];
        const double n  = (double)N2;
        sh_mean = 2.0 * S / n - 2.0 * V2 / (n * n);
    }
    __syncthreads();
    const double mean = sh_mean;
    double inva[3];
    inva[0] = 1.0 / (2.0 * 0.5 * mean);
    inva[1] = 1.0 / (2.0 * 1.0 * mean);
    inva[2] = 1.0 / (2.0 * 2.0 * mean);

    double acc = 0.0;
    for (int i = tid; i < B; i += 1024) {
        const int j = (i + 1) & (B - 1);
        const double d_ss = fmax((double)sqs[i] + (double)sqs[j] - 2.0 * (double)dss[i], 0.0);
        const double d_tt = fmax((double)sqt[i] + (double)sqt[j] - 2.0 * (double)dtt[i], 0.0);
        const double d_st = fmax((double)sqs[i] + (double)sqt[j] - 2.0 * (double)dst[i], 0.0);
        const double d_ts = fmax((double)sqs[j] + (double)sqt[i] - 2.0 * (double)dts[i], 0.0);
#pragma unroll
        for (int a = 0; a < 3; ++a)
            acc += exp(-d_ss * inva[a]) + exp(-d_tt * inva[a])
                 - exp(-d_st * inva[a]) - exp(-d_ts * inva[a]);
    }
    __syncthreads();   // red[] reuse
    red[tid] = acc;
    __syncthreads();
    for (int off = 512; off > 0; off >>= 1) {
        if (tid < off) red[tid] += red[tid + off];
        __syncthreads();
    }
    if (tid == 0) out[0] = (float)(red[0] / (double)B);
}

extern "C" void kernel_launch(void* const* d_in, const int* in_sizes, int n_in,
                              void* d_out, int out_size, void* d_ws, size_t ws_size,
                              hipStream_t stream) {
    const float* zs = (const float*)d_in[0];
    const float* zt = (const float*)d_in[1];
    float* ws  = (float*)d_ws;
    float* out = (float*)d_out;

    hipLaunchKernelGGL(mmd_init_colsum, dim3(1), dim3(D), 0, stream, ws + 6 * B);
    hipLaunchKernelGGL(mmd_colsum, dim3(N2 / 16), dim3(D), 0, stream, zs, zt, ws + 6 * B);
    hipLaunchKernelGGL(mmd_dots, dim3(B), dim3(256), 0, stream, zs, zt, ws);
    hipLaunchKernelGGL(mmd_finalize, dim3(1), dim3(1024), 0, stream, ws, out);
}